// Round 7
// baseline (537.683 us; speedup 1.0000x reference)
//
#include <hip/hip_runtime.h>
#include <cstdint>

#define NQ    8192
#define NNEG  16384
#define DIM   128
#define SPLIT 16
#define CHUNK (NNEG / SPLIT)          // 1024 negs per chunk
#define NBLK  (NQ / 128 * SPLIT)      // 1024 main blocks
// (1/TAU) * log2(e): MFMA output is directly the base-2 exponent
#define K_SCALE 7.2134752044448169f
#define LN2     0.69314718055994531f
#define BAND    20.0f                 // skip scores < M - 20 (log2): err <= ln(1+2^-6)

typedef __attribute__((ext_vector_type(8))) int   i32x8;
typedef __attribute__((ext_vector_type(4))) float f32x4;

union U8 { i32x8 v; int4 h[2]; };

__device__ inline void async_load16(const void* g, void* l) {
    __builtin_amdgcn_global_load_lds(
        (const __attribute__((address_space(1))) void*)g,
        (__attribute__((address_space(3))) void*)l, 16, 0, 0);
}

// log2 of a positive double via exponent extraction + f32 mantissa log
__device__ inline float log2_pos_d(double x) {
    long long b = __double_as_longlong(x);
    int e = (int)((b >> 52) & 2047) - 1023;
    double mant = __longlong_as_double((b & 0xFFFFFFFFFFFFFLL) | 0x3FF0000000000000LL);
    return (float)e + __log2f((float)mant);
}

// ---------------- kernel 1: convert to fp8 IN FRAGMENT ORDER + posdot + ws init ----
// One block per 16-row group (2 KB fp8 out). Blocks 0..511: q; 512..1535: neg.
// Fragment order per group: plane p (0/1), slot lane L=(quad*16+c0) holds row c0,
// k in [quad*32 + p*16, +16). Main reads h[p] at group*2048 + p*1024 + lane*16.
__global__ __launch_bounds__(256) void iw_prep(
    const float* __restrict__ q, const float* __restrict__ p,
    const float* __restrict__ neg,
    unsigned char* __restrict__ qb8f, unsigned char* __restrict__ nb8f,
    float* __restrict__ posdot, double* __restrict__ rowsum, int* __restrict__ counter)
{
    __shared__ unsigned char ldsb[2048];
    const int tid = threadIdx.x;
    const int g   = blockIdx.x;
    const int r   = tid >> 4;          // row within group
    const int j   = tid & 15;          // 8-float chunk within row
    const int quad = j >> 2, pl = (j >> 1) & 1, half = j & 1;
    const int ldsoff = pl * 1024 + (quad * 16 + r) * 16 + half * 8;

    if (g < NQ / 16) {
        const float4* src = (const float4*)(q + ((size_t)(g * 16 + r) * DIM + j * 8));
        float4 v0 = src[0], v1 = src[1];
        int w0 = __builtin_amdgcn_cvt_pk_fp8_f32(v0.x * K_SCALE, v0.y * K_SCALE, 0, false);
        w0     = __builtin_amdgcn_cvt_pk_fp8_f32(v0.z * K_SCALE, v0.w * K_SCALE, w0, true);
        int w1 = __builtin_amdgcn_cvt_pk_fp8_f32(v1.x * K_SCALE, v1.y * K_SCALE, 0, false);
        w1     = __builtin_amdgcn_cvt_pk_fp8_f32(v1.z * K_SCALE, v1.w * K_SCALE, w1, true);
        *(int2*)(ldsb + ldsoff) = make_int2(w0, w1);
        const float4* ps = (const float4*)(p + ((size_t)(g * 16 + r) * DIM + j * 8));
        float4 p0 = ps[0], p1 = ps[1];
        float d = fmaf(v0.x, p0.x, fmaf(v0.y, p0.y, fmaf(v0.z, p0.z, v0.w * p0.w)));
        d = fmaf(v1.x, p1.x, fmaf(v1.y, p1.y, fmaf(v1.z, p1.z, fmaf(v1.w, p1.w, d))));
#pragma unroll
        for (int s = 1; s < 16; s <<= 1) d += __shfl_xor(d, s, 64);
        if (j == 0) posdot[g * 16 + r] = d;
        __syncthreads();
        ((int2*)(qb8f + (size_t)g * 2048))[tid] = ((const int2*)ldsb)[tid];
    } else {
        const int gg = g - NQ / 16;    // 0..1023
        if (gg < 32) rowsum[gg * 256 + tid] = 0.0;
        if (gg == 32 && tid == 0) *counter = 0;
        const float4* src = (const float4*)(neg + ((size_t)(gg * 16 + r) * DIM + j * 8));
        float4 v0 = src[0], v1 = src[1];
        int w0 = __builtin_amdgcn_cvt_pk_fp8_f32(v0.x, v0.y, 0, false);
        w0     = __builtin_amdgcn_cvt_pk_fp8_f32(v0.z, v0.w, w0, true);
        int w1 = __builtin_amdgcn_cvt_pk_fp8_f32(v1.x, v1.y, 0, false);
        w1     = __builtin_amdgcn_cvt_pk_fp8_f32(v1.z, v1.w, w1, true);
        *(int2*)(ldsb + ldsoff) = make_int2(w0, w1);
        __syncthreads();
        ((int2*)(nb8f + (size_t)gg * 2048))[tid] = ((const int2*)ldsb)[tid];
    }
}

// ---------------- kernel 2: two-pass flash-LSE (max pass, banded-sum pass) --------
// grid (64, 16). Wave split 2x2: rowhalf=w>>1 owns 64 rows, colhalf=w&1 owns 32 of
// each 64-neg tile's columns. rs=4 row-frags, ns=2 col-groups per wave.
__global__ __launch_bounds__(256, 4) void iw_main(
    const unsigned char* __restrict__ qb8f, const unsigned char* __restrict__ nb8f,
    const float* __restrict__ posdot, double* __restrict__ rowsum,
    int* __restrict__ counter, float* __restrict__ out)
{
    constexpr int NIT = CHUNK / 64;   // 16 tiles of 64 negs
    __shared__ alignas(16) unsigned char n_lds[2 * 8192];   // dbuf 2 x 8 KB
    __shared__ float maxbuf[2][128];
    __shared__ int isLast;

    const int tid  = threadIdx.x;
    const int lane = tid & 63;
    const int w    = tid >> 6;
    const int rowhalf = w >> 1, colhalf = w & 1;
    const int quad = lane >> 4;
    const int c0   = lane & 15;
    const int row0 = blockIdx.x * 128;

    // ---- A fragments (4 groups of 16 rows), fragment-order, coalesced ----
    const int4* abase = (const int4*)qb8f + (size_t)(blockIdx.x * 8 + rowhalf * 4) * 128;
    U8 afrag[4];
#pragma unroll
    for (int rs = 0; rs < 4; ++rs) {
        afrag[rs].h[0] = abase[rs * 128 + lane];
        afrag[rs].h[1] = abase[rs * 128 + 64 + lane];
    }

    const unsigned char* bsrc = nb8f + (size_t)blockIdx.y * (CHUNK * DIM);
    const int stage_src_off = tid * 16;            // within a tile (8 KB)
    const int stage_dst_off = w * 1024;            // wave-uniform; HW adds lane*16

#define STAGE(t, buf)                                                          \
    do {                                                                       \
        async_load16(bsrc + (size_t)(t) * 8192 + stage_src_off,                \
                     n_lds + (buf) + stage_dst_off);                           \
        async_load16(bsrc + (size_t)(t) * 8192 + 4096 + stage_src_off,         \
                     n_lds + (buf) + 4096 + stage_dst_off);                    \
    } while (0)

    const f32x4 zero4 = {0.f, 0.f, 0.f, 0.f};
    const int boff0 = (colhalf * 2) * 2048 + lane * 16;   // group colhalf*2
    const int boff1 = (colhalf * 2 + 1) * 2048 + lane * 16;

    float m_s[4][4];     // pass A: running max; after merge: chunk row-max M
#pragma unroll
    for (int rs = 0; rs < 4; ++rs)
#pragma unroll
        for (int i = 0; i < 4; ++i) m_s[rs][i] = -1e30f;

    // ================= PASS A: row max =================
    STAGE(0, 0);
    __syncthreads();
    for (int it = 0; it < NIT; ++it) {
        const int buf = (it & 1) * 8192;
        if (it + 1 < NIT) STAGE(it + 1, 8192 - buf);
        U8 b[2];
        b[0].h[0] = *(const int4*)(n_lds + buf + boff0);
        b[0].h[1] = *(const int4*)(n_lds + buf + boff0 + 1024);
        b[1].h[0] = *(const int4*)(n_lds + buf + boff1);
        b[1].h[1] = *(const int4*)(n_lds + buf + boff1 + 1024);

        f32x4 acc[4][2];
#pragma unroll
        for (int rs = 0; rs < 4; ++rs)
#pragma unroll
            for (int ns = 0; ns < 2; ++ns)
                acc[rs][ns] = __builtin_amdgcn_mfma_scale_f32_16x16x128_f8f6f4(
                    afrag[rs].v, b[ns].v, zero4, 0, 0, 0, 127, 0, 127);
#pragma unroll
        for (int rs = 0; rs < 4; ++rs)
#pragma unroll
            for (int i = 0; i < 4; ++i)
                m_s[rs][i] = fmaxf(m_s[rs][i], fmaxf(acc[rs][0][i], acc[rs][1][i]));
        __syncthreads();
    }

    // ---- merge max: 16 lanes (cols) then across the two col-waves via LDS ----
#pragma unroll
    for (int rs = 0; rs < 4; ++rs)
#pragma unroll
        for (int i = 0; i < 4; ++i) {
            float m = m_s[rs][i];
#pragma unroll
            for (int s = 1; s < 16; s <<= 1) m = fmaxf(m, __shfl_xor(m, s, 64));
            m_s[rs][i] = m;
            if (c0 == 0) maxbuf[colhalf][rowhalf * 64 + rs * 16 + quad * 4 + i] = m;
        }
    __syncthreads();
#pragma unroll
    for (int rs = 0; rs < 4; ++rs)
#pragma unroll
        for (int i = 0; i < 4; ++i) {
            int r = rowhalf * 64 + rs * 16 + quad * 4 + i;
            m_s[rs][i] = fmaxf(maxbuf[0][r], maxbuf[1][r]);   // chunk row-max M
        }

    // ================= PASS B: banded exact sum =================
    float l_s[4][4];
#pragma unroll
    for (int rs = 0; rs < 4; ++rs)
#pragma unroll
        for (int i = 0; i < 4; ++i) l_s[rs][i] = 0.f;

    __syncthreads();
    STAGE(0, 0);
    __syncthreads();
    for (int it = 0; it < NIT; ++it) {
        const int buf = (it & 1) * 8192;
        if (it + 1 < NIT) STAGE(it + 1, 8192 - buf);
        U8 b[2];
        b[0].h[0] = *(const int4*)(n_lds + buf + boff0);
        b[0].h[1] = *(const int4*)(n_lds + buf + boff0 + 1024);
        b[1].h[0] = *(const int4*)(n_lds + buf + boff1);
        b[1].h[1] = *(const int4*)(n_lds + buf + boff1 + 1024);

        f32x4 acc[4][2];
#pragma unroll
        for (int rs = 0; rs < 4; ++rs)
#pragma unroll
            for (int ns = 0; ns < 2; ++ns)
                acc[rs][ns] = __builtin_amdgcn_mfma_scale_f32_16x16x128_f8f6f4(
                    afrag[rs].v, b[ns].v, zero4, 0, 0, 0, 127, 0, 127);

        // skip test: any score within BAND of its row's chunk max?
        float t = -1e30f;
#pragma unroll
        for (int rs = 0; rs < 4; ++rs)
#pragma unroll
            for (int i = 0; i < 4; ++i)
                t = fmaxf(t, fmaxf(acc[rs][0][i], acc[rs][1][i]) - m_s[rs][i]);
        if (__any(t > -BAND)) {
#pragma unroll
            for (int rs = 0; rs < 4; ++rs)
#pragma unroll
                for (int i = 0; i < 4; ++i)
                    l_s[rs][i] += __builtin_amdgcn_exp2f(acc[rs][0][i] - m_s[rs][i])
                                + __builtin_amdgcn_exp2f(acc[rs][1][i] - m_s[rs][i]);
        }
        __syncthreads();
    }

    // ---- epilogue: sum l over 16 col-lanes; add l * 2^M to rowsum (f64) ----
#pragma unroll
    for (int rs = 0; rs < 4; ++rs)
#pragma unroll
        for (int i = 0; i < 4; ++i) {
            float l = l_s[rs][i];
#pragma unroll
            for (int s = 1; s < 16; s <<= 1) l += __shfl_xor(l, s, 64);
            if (c0 == 0) {
                float m  = m_s[rs][i];
                float ef = floorf(m);
                float lf = l * __builtin_amdgcn_exp2f(m - ef);
                double sc = __longlong_as_double((long long)(1023 + (int)ef) << 52);
                int grow = row0 + rowhalf * 64 + rs * 16 + quad * 4 + i;
                atomicAdd(&rowsum[grow], (double)lf * sc);
            }
        }

    // ---- last-block finalize ----
    __threadfence();
    __syncthreads();
    if (tid == 0) isLast = (atomicAdd(counter, 1) == NBLK - 1) ? 1 : 0;
    __syncthreads();
    if (!isLast) return;
    __threadfence();

    float v = 0.f;
#pragma unroll
    for (int rr = 0; rr < NQ / 256; ++rr) {
        int row = rr * 256 + tid;
        double s = __hip_atomic_load(&rowsum[row], __ATOMIC_RELAXED, __HIP_MEMORY_SCOPE_AGENT);
        v += LN2 * log2_pos_d(s) - 5.0f * posdot[row];
    }
#pragma unroll
    for (int s = 32; s >= 1; s >>= 1) v += __shfl_xor(v, s, 64);
    __shared__ float red[4];
    if ((tid & 63) == 0) red[tid >> 6] = v;
    __syncthreads();
    if (tid == 0) out[0] = (red[0] + red[1] + red[2] + red[3]) * (1.0f / (float)NQ);
}

// ---------------- launch ----------------
extern "C" void kernel_launch(void* const* d_in, const int* in_sizes, int n_in,
                              void* d_out, int out_size, void* d_ws, size_t ws_size,
                              hipStream_t stream) {
    const float* q   = (const float*)d_in[0];
    const float* pos = (const float*)d_in[1];
    const float* neg = (const float*)d_in[2];
    float* out = (float*)d_out;

    unsigned char* qb8f = (unsigned char*)d_ws;                      // 1 MB
    unsigned char* nb8f = qb8f + (size_t)NQ * DIM;                   // 2 MB
    float*  posdot = (float*)(nb8f + (size_t)NNEG * DIM);            // 32 KB
    double* rowsum = (double*)(posdot + NQ);                         // 64 KB
    int*    counter = (int*)(rowsum + NQ);                           // 4 B

    iw_prep <<<NQ / 16 + NNEG / 16, 256, 0, stream>>>(q, pos, neg, qb8f, nb8f,
                                                      posdot, rowsum, counter);
    iw_main <<<dim3(NQ / 128, SPLIT), 256, 0, stream>>>(qb8f, nb8f, posdot,
                                                        rowsum, counter, out);
}

// Round 8
// 162.258 us; speedup vs baseline: 3.3138x; 3.3138x over previous
//
#include <hip/hip_runtime.h>
#include <cstdint>

#define NQ    8192
#define NNEG  16384
#define DIM   128
#define SPLIT 16
#define CHUNK (NNEG / SPLIT)          // 1024 negs per chunk
#define NBLK  (NQ / 128 * SPLIT)      // 1024 main blocks
// (1/TAU) * log2(e): MFMA output is directly the base-2 exponent
#define K_SCALE 7.2134752044448169f
#define LN2     0.69314718055994531f

typedef __attribute__((ext_vector_type(8))) int   i32x8;
typedef __attribute__((ext_vector_type(4))) float f32x4;

union U8 { i32x8 v; int4 h[2]; };

__device__ inline void async_load16(const void* g, void* l) {
    __builtin_amdgcn_global_load_lds(
        (const __attribute__((address_space(1))) void*)g,
        (__attribute__((address_space(3))) void*)l, 16, 0, 0);
}

// log2 of a positive double via exponent extraction + f32 mantissa log
__device__ inline float log2_pos_d(double x) {
    long long b = __double_as_longlong(x);
    int e = (int)((b >> 52) & 2047) - 1023;
    double mant = __longlong_as_double((b & 0xFFFFFFFFFFFFFLL) | 0x3FF0000000000000LL);
    return (float)e + __log2f((float)mant);
}

// ---------------- kernel 1: convert to fp8 IN FRAGMENT ORDER + posdot + ws init ----
// One block per 16-row group (2 KB fp8 out). Blocks 0..511: q; 512..1535: neg.
// Fragment order per group: plane p (0/1), slot lane L=(quad*16+c0) holds row c0,
// k in [quad*32 + p*16, +16). Consumers read h[p] at group*2048 + p*1024 + lane*16.
__global__ __launch_bounds__(256) void iw_prep(
    const float* __restrict__ q, const float* __restrict__ p,
    const float* __restrict__ neg,
    unsigned char* __restrict__ qb8f, unsigned char* __restrict__ nb8f,
    float* __restrict__ posdot, double* __restrict__ rowsum, int* __restrict__ counter)
{
    __shared__ unsigned char ldsb[2048];
    const int tid = threadIdx.x;
    const int g   = blockIdx.x;
    const int r   = tid >> 4;          // row within group
    const int j   = tid & 15;          // 8-float chunk within row
    const int quad = j >> 2, pl = (j >> 1) & 1, half = j & 1;
    const int ldsoff = pl * 1024 + (quad * 16 + r) * 16 + half * 8;

    if (g < NQ / 16) {
        const float4* src = (const float4*)(q + ((size_t)(g * 16 + r) * DIM + j * 8));
        float4 v0 = src[0], v1 = src[1];
        int w0 = __builtin_amdgcn_cvt_pk_fp8_f32(v0.x * K_SCALE, v0.y * K_SCALE, 0, false);
        w0     = __builtin_amdgcn_cvt_pk_fp8_f32(v0.z * K_SCALE, v0.w * K_SCALE, w0, true);
        int w1 = __builtin_amdgcn_cvt_pk_fp8_f32(v1.x * K_SCALE, v1.y * K_SCALE, 0, false);
        w1     = __builtin_amdgcn_cvt_pk_fp8_f32(v1.z * K_SCALE, v1.w * K_SCALE, w1, true);
        *(int2*)(ldsb + ldsoff) = make_int2(w0, w1);
        const float4* ps = (const float4*)(p + ((size_t)(g * 16 + r) * DIM + j * 8));
        float4 p0 = ps[0], p1 = ps[1];
        float d = fmaf(v0.x, p0.x, fmaf(v0.y, p0.y, fmaf(v0.z, p0.z, v0.w * p0.w)));
        d = fmaf(v1.x, p1.x, fmaf(v1.y, p1.y, fmaf(v1.z, p1.z, fmaf(v1.w, p1.w, d))));
#pragma unroll
        for (int s = 1; s < 16; s <<= 1) d += __shfl_xor(d, s, 64);
        if (j == 0) posdot[g * 16 + r] = d;
        __syncthreads();
        ((int2*)(qb8f + (size_t)g * 2048))[tid] = ((const int2*)ldsb)[tid];
    } else {
        const int gg = g - NQ / 16;    // 0..1023
        if (gg < 32) rowsum[gg * 256 + tid] = 0.0;
        if (gg == 32 && tid == 0) *counter = 0;
        const float4* src = (const float4*)(neg + ((size_t)(gg * 16 + r) * DIM + j * 8));
        float4 v0 = src[0], v1 = src[1];
        int w0 = __builtin_amdgcn_cvt_pk_fp8_f32(v0.x, v0.y, 0, false);
        w0     = __builtin_amdgcn_cvt_pk_fp8_f32(v0.z, v0.w, w0, true);
        int w1 = __builtin_amdgcn_cvt_pk_fp8_f32(v1.x, v1.y, 0, false);
        w1     = __builtin_amdgcn_cvt_pk_fp8_f32(v1.z, v1.w, w1, true);
        *(int2*)(ldsb + ldsoff) = make_int2(w0, w1);
        __syncthreads();
        ((int2*)(nb8f + (size_t)gg * 2048))[tid] = ((const int2*)ldsb)[tid];
    }
}

// ---------------- kernel 2: flash-LSE main (R3 skeleton, fragment-order LDS) ------
// grid (64, 16): blockIdx.x = 128-row block, blockIdx.y = 1024-neg chunk.
// Wave w owns rows w*32..w*32+31 (2 groups); all waves share the 64-neg B tile.
__global__ __launch_bounds__(256, 4) void iw_main(
    const unsigned char* __restrict__ qb8f, const unsigned char* __restrict__ nb8f,
    const float* __restrict__ posdot, double* __restrict__ rowsum,
    int* __restrict__ counter, float* __restrict__ out)
{
    constexpr int NIT = CHUNK / 64;   // 16 tiles of 64 negs (8 KB fp8 each)
    __shared__ alignas(16) unsigned char n_lds[2 * 8192];   // dbuf 2 x 8 KB
    __shared__ int isLast;

    const int tid  = threadIdx.x;
    const int lane = tid & 63;
    const int w    = tid >> 6;
    const int quad = lane >> 4;
    const int c0   = lane & 15;
    const int row0 = blockIdx.x * 128;

    // ---- A fragments (2 groups of 16 rows/wave), fragment-order, coalesced ----
    const int4* abase = (const int4*)qb8f + (size_t)(blockIdx.x * 8 + w * 2) * 128;
    U8 afrag[2];
#pragma unroll
    for (int rs = 0; rs < 2; ++rs) {
        afrag[rs].h[0] = abase[rs * 128 + lane];
        afrag[rs].h[1] = abase[rs * 128 + 64 + lane];
    }

    // ---- staging: linear 8 KB tile copy; thread tid covers bytes [tid*16, +16)x2 ----
    const unsigned char* bsrc = nb8f + (size_t)blockIdx.y * (CHUNK * DIM);
    const int src_off = tid * 16;     // thread's slice within the tile
    const int dst_off = w * 1024;     // wave-uniform base; HW adds lane*16

    // prefetch tile 0 into buf 0
    async_load16(bsrc + src_off,        n_lds + dst_off);
    async_load16(bsrc + 4096 + src_off, n_lds + 4096 + dst_off);
    __syncthreads();

    float m_s[2][4], l_s[2][4];
#pragma unroll
    for (int rs = 0; rs < 2; ++rs)
#pragma unroll
        for (int i = 0; i < 4; ++i) { m_s[rs][i] = -1e30f; l_s[rs][i] = 0.f; }

    const f32x4 zero4 = {0.f, 0.f, 0.f, 0.f};
    const int bl = lane * 16;         // conflict-free ds_read_b128 base

    for (int it = 0; it < NIT; ++it) {
        const int buf = (it & 1) * 8192;
        if (it + 1 < NIT) {           // async prefetch next tile into other buffer
            const unsigned char* s = bsrc + (size_t)(it + 1) * 8192;
            const int nbuf = 8192 - buf;
            async_load16(s + src_off,        n_lds + nbuf + dst_off);
            async_load16(s + 4096 + src_off, n_lds + nbuf + 4096 + dst_off);
        }

        f32x4 acc[2][4];
#pragma unroll
        for (int ns = 0; ns < 4; ++ns) {
            U8 b;                     // group ns, planes 0/1: const offsets, no addr math
            b.h[0] = *(const int4*)(n_lds + buf + ns * 2048 + bl);
            b.h[1] = *(const int4*)(n_lds + buf + ns * 2048 + 1024 + bl);
            acc[0][ns] = __builtin_amdgcn_mfma_scale_f32_16x16x128_f8f6f4(
                afrag[0].v, b.v, zero4, 0, 0, 0, 127, 0, 127);
            acc[1][ns] = __builtin_amdgcn_mfma_scale_f32_16x16x128_f8f6f4(
                afrag[1].v, b.v, zero4, 0, 0, 0, 127, 0, 127);
        }

        // per-lane online logsumexp (exp2-domain, pure VALU; overlaps prefetch)
#pragma unroll
        for (int rs = 0; rs < 2; ++rs) {
#pragma unroll
            for (int i = 0; i < 4; ++i) {
                float y0 = acc[rs][0][i], y1 = acc[rs][1][i];
                float y2 = acc[rs][2][i], y3 = acc[rs][3][i];
                float m0 = m_s[rs][i];
                float nm = fmaxf(fmaxf(fmaxf(y0, y1), fmaxf(y2, y3)), m0);
                float t  = __builtin_amdgcn_exp2f(y0 - nm) + __builtin_amdgcn_exp2f(y1 - nm)
                         + __builtin_amdgcn_exp2f(y2 - nm) + __builtin_amdgcn_exp2f(y3 - nm);
                l_s[rs][i] = l_s[rs][i] * __builtin_amdgcn_exp2f(m0 - nm) + t;
                m_s[rs][i] = nm;
            }
        }
        __syncthreads();   // drains prefetch (vmcnt) + ds_reads; buffer swap safe
    }

    // ---- merge (m,l) across the 16 col-lanes; add l * 2^m to rowsum (f64) ----
#pragma unroll
    for (int rs = 0; rs < 2; ++rs) {
#pragma unroll
        for (int i = 0; i < 4; ++i) {
            float m = m_s[rs][i], l = l_s[rs][i];
#pragma unroll
            for (int s = 1; s < 16; s <<= 1) {
                float om = __shfl_xor(m, s, 64);
                float ol = __shfl_xor(l, s, 64);
                float nm = fmaxf(m, om);
                l = l * __builtin_amdgcn_exp2f(m - nm) + ol * __builtin_amdgcn_exp2f(om - nm);
                m = nm;
            }
            if (c0 == 0) {
                float ef  = floorf(m);
                float lf  = l * __builtin_amdgcn_exp2f(m - ef);
                double sc = __longlong_as_double((long long)(1023 + (int)ef) << 52);
                int grow  = row0 + w * 32 + rs * 16 + quad * 4 + i;
                atomicAdd(&rowsum[grow], (double)lf * sc);
            }
        }
    }

    // ---- last-block finalize ----
    __threadfence();
    __syncthreads();
    if (tid == 0) isLast = (atomicAdd(counter, 1) == NBLK - 1) ? 1 : 0;
    __syncthreads();
    if (!isLast) return;
    __threadfence();

    float v = 0.f;
#pragma unroll
    for (int rr = 0; rr < NQ / 256; ++rr) {
        int row = rr * 256 + tid;
        double s = __hip_atomic_load(&rowsum[row], __ATOMIC_RELAXED, __HIP_MEMORY_SCOPE_AGENT);
        v += LN2 * log2_pos_d(s) - 5.0f * posdot[row];
    }
#pragma unroll
    for (int s = 32; s >= 1; s >>= 1) v += __shfl_xor(v, s, 64);
    __shared__ float red[4];
    if ((tid & 63) == 0) red[tid >> 6] = v;
    __syncthreads();
    if (tid == 0) out[0] = (red[0] + red[1] + red[2] + red[3]) * (1.0f / (float)NQ);
}

// ---------------- launch ----------------
extern "C" void kernel_launch(void* const* d_in, const int* in_sizes, int n_in,
                              void* d_out, int out_size, void* d_ws, size_t ws_size,
                              hipStream_t stream) {
    const float* q   = (const float*)d_in[0];
    const float* pos = (const float*)d_in[1];
    const float* neg = (const float*)d_in[2];
    float* out = (float*)d_out;

    unsigned char* qb8f = (unsigned char*)d_ws;                      // 1 MB
    unsigned char* nb8f = qb8f + (size_t)NQ * DIM;                   // 2 MB
    float*  posdot = (float*)(nb8f + (size_t)NNEG * DIM);            // 32 KB
    double* rowsum = (double*)(posdot + NQ);                         // 64 KB
    int*    counter = (int*)(rowsum + NQ);                           // 4 B

    iw_prep <<<NQ / 16 + NNEG / 16, 256, 0, stream>>>(q, pos, neg, qb8f, nb8f,
                                                      posdot, rowsum, counter);
    iw_main <<<dim3(NQ / 128, SPLIT), 256, 0, stream>>>(qb8f, nb8f, posdot,
                                                        rowsum, counter, out);
}